// Round 12
// baseline (180.641 us; speedup 1.0000x reference)
//
#include <hip/hip_runtime.h>
#include <math.h>

#define NSEQ   4096
#define DMODEL 640
#define NHEAD  8
#define DHEAD  64
#define INNER  512   // NHEAD*DHEAD
#define KVSPLIT 2

typedef _Float16 f16;
typedef _Float16 f16x8 __attribute__((ext_vector_type(8)));
typedef _Float16 f16x4 __attribute__((ext_vector_type(4)));
typedef float    f32x4 __attribute__((ext_vector_type(4)));

#define MFMA16(a, b, c) __builtin_amdgcn_mfma_f32_16x16x32_f16((a), (b), (c), 0, 0, 0)

// softmax scale 1/8 folded with log2(e): softmax runs in exp2 domain
#define QSCALE 0.18033688011112042f

// global -> LDS direct copy, 16B/lane, wave-uniform LDS base.
__device__ __forceinline__ void gl16(const f16* g, f16* l) {
    __builtin_amdgcn_global_load_lds(
        (const __attribute__((address_space(1))) unsigned int*)g,
        (__attribute__((address_space(3))) unsigned int*)l, 16, 0, 0);
}

// ---------------------------------------------------------------------------
// Prep: transpose+convert all four weights in ONE launch.
// z=0..2: Wq/Wk/Wv f32 [640][512] -> f16 [512][640]; z=3: Wo [512][640]->[640][512]
// ---------------------------------------------------------------------------
__global__ __launch_bounds__(256) void transpose_cvtW(
    const float* __restrict__ Wq, const float* __restrict__ Wk,
    const float* __restrict__ Wv, const float* __restrict__ Wo,
    f16* __restrict__ WTq, f16* __restrict__ WTk, f16* __restrict__ WTv,
    f16* __restrict__ WoT) {
    __shared__ __align__(16) f16 T[64][72];
    const int bz = blockIdx.z;
    const float* src = bz == 0 ? Wq : bz == 1 ? Wk : bz == 2 ? Wv : Wo;
    f16* dst = bz == 0 ? WTq : bz == 1 ? WTk : bz == 2 ? WTv : WoT;
    const int R = (bz < 3) ? DMODEL : INNER;   // src rows
    const int C = (bz < 3) ? INNER : DMODEL;   // src cols
    const int c0 = blockIdx.x * 64, r0 = blockIdx.y * 64;
    if (c0 >= C || r0 >= R) return;            // block-uniform early out
    const int t = threadIdx.x;
    {
        int r = t >> 2, cb = (t & 3) * 16;
#pragma unroll
        for (int i = 0; i < 16; i += 4) {
            float4 v = *(const float4*)&src[(size_t)(r0 + r) * C + c0 + cb + i];
            T[cb + i + 0][r] = (f16)v.x;
            T[cb + i + 1][r] = (f16)v.y;
            T[cb + i + 2][r] = (f16)v.z;
            T[cb + i + 3][r] = (f16)v.w;
        }
    }
    __syncthreads();
    {
        int c = t >> 2, rb = (t & 3) * 16;
        f16* d = dst + (size_t)(c0 + c) * R + r0 + rb;
        *(f16x8*)d = *(const f16x8*)&T[c][rb];
        *(f16x8*)(d + 8) = *(const f16x8*)&T[c][rb + 8];
    }
}

// ---------------------------------------------------------------------------
// QKV projection with FUSED x conversion: A staged from f32 x via registers
// (convert f32->f16 in-kernel, swizzled ds_write) — cvt_x kernel and xh
// buffer eliminated. B staged via gl16. Fragment-reuse M128xN64, K=64.
// Outputs: z=0 Q (prescaled) [h][n][d], z=1 K [h][n][d], z=2 V^T [h][d][n].
// ---------------------------------------------------------------------------
__global__ __launch_bounds__(256) void qkv_gemm16(
    const float* __restrict__ x,
    const f16* __restrict__ WTq, const f16* __restrict__ WTk,
    const f16* __restrict__ WTv,
    f16* __restrict__ q16, f16* __restrict__ k16, f16* __restrict__ vT16)
{
    __shared__ __align__(16) f16 S[12288];   // A: [0,8192) B: [8192,12288)
    f16* Xs = S;                              // [128 rows][64 cols] swizzled
    f16* Ws = S + 8192;                       // [64][64] swizzled

    const int bx = blockIdx.x;               // head / N-tile
    const int by = blockIdx.y;               // M-tile (128 rows)
    const int bz = blockIdx.z;               // 0=Q 1=K 2=V
    const f16* WT = (bz == 0) ? WTq : (bz == 1) ? WTk : WTv;

    const int tid = threadIdx.x;
    const int w = tid >> 6, lane = tid & 63;
    const int lr = lane & 15, lc = lane >> 4;
    const int srow8 = lane >> 3;
    const int le = 8 * ((lane & 7) ^ srow8);
    const int swz0 = 8 * (lc ^ (lr & 7));
    const int swz1 = 8 * ((lc + 4) ^ (lr & 7));
    const int m0 = by * 128, n0 = bx * 64;

    // A reg-staging indices: thread owns row arow, 4 col-groups ag..ag+3
    const int arow = tid >> 1;               // 0..127
    const int ag   = (tid & 1) * 4;          // group base 0 or 4

    f32x4 acc[2][4] = {};

    for (int s = 0; s < DMODEL / 64; ++s) {
        const int k0 = s * 64;
        // ---- A: x f32 -> regs -> f16 -> swizzled ds_write (4 x b128)
        {
            const float* xs = x + (size_t)(m0 + arow) * DMODEL + k0 + ag * 8;
            float4 xa[8];
#pragma unroll
            for (int i = 0; i < 8; ++i) xa[i] = *(const float4*)&xs[i * 4];
#pragma unroll
            for (int i = 0; i < 4; ++i) {
                f16x8 v = {(f16)xa[2 * i].x, (f16)xa[2 * i].y,
                           (f16)xa[2 * i].z, (f16)xa[2 * i].w,
                           (f16)xa[2 * i + 1].x, (f16)xa[2 * i + 1].y,
                           (f16)xa[2 * i + 1].z, (f16)xa[2 * i + 1].w};
                *(f16x8*)&Xs[arow * 64 + 8 * ((ag + i) ^ (arow & 7))] = v;
            }
        }
        // ---- B: gl16 (pre-swizzled source offset, linear LDS dest)
#pragma unroll
        for (int c = 0; c < 2; ++c) {
            const int cc = 2 * w + c;
            gl16(WT + (size_t)(n0 + cc * 8 + srow8) * DMODEL + k0 + le,
                 &Ws[cc * 512]);
        }
        __syncthreads();
        f16x8 a0[2], a1[2];
#pragma unroll
        for (int g = 0; g < 2; ++g) {
            const int row = 32 * w + 16 * g + lr;
            a0[g] = *(const f16x8*)&Xs[row * 64 + swz0];
            a1[g] = *(const f16x8*)&Xs[row * 64 + swz1];
        }
#pragma unroll
        for (int nt = 0; nt < 4; ++nt) {
            f16x8 b0 = *(const f16x8*)&Ws[(nt * 16 + lr) * 64 + swz0];
            f16x8 b1 = *(const f16x8*)&Ws[(nt * 16 + lr) * 64 + swz1];
#pragma unroll
            for (int g = 0; g < 2; ++g)
                acc[g][nt] = MFMA16(a1[g], b1, MFMA16(a0[g], b0, acc[g][nt]));
        }
        __syncthreads();
    }

    const float sc = (bz == 0) ? QSCALE : 1.0f;
    if (bz < 2) {
#pragma unroll
        for (int g = 0; g < 2; ++g)
#pragma unroll
            for (int nt = 0; nt < 4; ++nt)
#pragma unroll
                for (int r = 0; r < 4; ++r)
                    S[(32 * w + 16 * g + 4 * lc + r) * 72 + nt * 16 + lr] =
                        (f16)(acc[g][nt][r] * sc);
        __syncthreads();
        f16* ob = ((bz == 0) ? q16 : k16) + (size_t)bx * NSEQ * DHEAD;
#pragma unroll
        for (int p = 0; p < 2; ++p) {
            const int rr = p * 64 + (tid >> 2), cb = (tid & 3) * 16;
            f16* dst = ob + (size_t)(m0 + rr) * DHEAD + cb;
            *(f16x8*)dst = *(const f16x8*)&S[rr * 72 + cb];
            *(f16x8*)(dst + 8) = *(const f16x8*)&S[rr * 72 + cb + 8];
        }
    } else {
#pragma unroll
        for (int g = 0; g < 2; ++g)
#pragma unroll
            for (int nt = 0; nt < 4; ++nt)
#pragma unroll
                for (int r = 0; r < 4; ++r)
                    S[(nt * 16 + lr) * 136 + 32 * w + 16 * g + 4 * lc + r] =
                        (f16)acc[g][nt][r];
        __syncthreads();
        const int rr = tid >> 2, cb = (tid & 3) * 32;
        f16* dst = vT16 + ((size_t)bx * DHEAD + rr) * NSEQ + m0 + cb;
        *(f16x8*)dst        = *(const f16x8*)&S[rr * 136 + cb];
        *(f16x8*)(dst + 8)  = *(const f16x8*)&S[rr * 136 + cb + 8];
        *(f16x8*)(dst + 16) = *(const f16x8*)&S[rr * 136 + cb + 16];
        *(f16x8*)(dst + 24) = *(const f16x8*)&S[rr * 136 + cb + 24];
    }
}

// ---------------------------------------------------------------------------
// Flash attention (round-11 T15 double-pipeline, unchanged).
// ---------------------------------------------------------------------------
__global__ __launch_bounds__(256, 2) void attn_fwd(
    const f16* __restrict__ q16, const f16* __restrict__ k16,
    const f16* __restrict__ vT16, f16* __restrict__ Opart,
    float* __restrict__ Ml)
{
    __shared__ __align__(16) f16 KsB[2][4096];   // [kv 64][d 64] swizzled
    __shared__ __align__(16) f16 VtB[4][4096];   // [d 64][kv 64] swizzled
    __shared__ __align__(16) f16 Ps[8192];       // [q 128][kv 64] swizzled

    const int lin = blockIdx.x + 32 * blockIdx.y + 256 * blockIdx.z;
    const int h  = lin & 7;
    const int qb = (lin >> 3) & 31;              // q-tile of 128 rows
    const int sp = lin >> 8;                     // kv half 0/1

    const int tid = threadIdx.x;
    const int w = tid >> 6, lane = tid & 63;
    const int lr = lane & 15, lc = lane >> 4;
    const int srow8 = lane >> 3;
    const int le = 8 * ((lane & 7) ^ srow8);
    const int swz0 = 8 * (lc ^ (lr & 7));
    const int swz1 = 8 * ((lc + 4) ^ (lr & 7));

    const f16* kp = k16 + ((size_t)h * NSEQ + sp * (NSEQ / KVSPLIT)) * DHEAD;
    const f16* vp = vT16 + (size_t)h * DHEAD * NSEQ + sp * (NSEQ / KVSPLIT);

    // Q fragments: wave rows qb*128 + 32w + 16g + lr, g=0,1 (prescaled)
    f16x8 qf[2][2];
#pragma unroll
    for (int g = 0; g < 2; ++g) {
        const f16* qp = q16 +
            ((size_t)h * NSEQ + qb * 128 + 32 * w + 16 * g + lr) * DHEAD;
        qf[g][0] = *(const f16x8*)&qp[lc * 8];
        qf[g][1] = *(const f16x8*)&qp[32 + lc * 8];
    }

    float m_run[2] = {-INFINITY, -INFINITY}, l_run[2] = {0.f, 0.f};
    f32x4 o[2][4] = {};
    f32x4 sA[2][4], sB[2][4];
    const int NT = NSEQ / KVSPLIT / 64;          // 32

#define PREFETCH(J, KB, VB) {                                                 \
    _Pragma("unroll")                                                         \
    for (int c = 0; c < 2; ++c) {                                             \
        const int cc = 2 * w + c;                                             \
        gl16(kp + (size_t)((J) * 64 + cc * 8 + srow8) * DHEAD + le,           \
             &KsB[KB][cc * 512]);                                             \
        gl16(vp + (size_t)(cc * 8 + srow8) * NSEQ + (J) * 64 + le,            \
             &VtB[VB][cc * 512]);                                             \
    } }

#define QKT(KB, S) {                                                          \
    const f32x4 z4 = {0.f, 0.f, 0.f, 0.f};                                    \
    _Pragma("unroll")                                                         \
    for (int t = 0; t < 4; ++t) {                                             \
        f16x8 ka = *(const f16x8*)&KsB[KB][(t * 16 + lr) * 64 + swz0];        \
        f16x8 kb = *(const f16x8*)&KsB[KB][(t * 16 + lr) * 64 + swz1];        \
        _Pragma("unroll")                                                     \
        for (int g = 0; g < 2; ++g)                                           \
            S[g][t] = MFMA16(kb, qf[g][1], MFMA16(ka, qf[g][0], z4));         \
    } }

#define FINISH(VB, S) {                                                       \
    float pm[2];                                                              \
    _Pragma("unroll")                                                         \
    for (int g = 0; g < 2; ++g) {                                             \
        float mm = S[g][0][0];                                                \
        _Pragma("unroll")                                                     \
        for (int t = 0; t < 4; ++t)                                           \
            _Pragma("unroll")                                                 \
            for (int r = 0; r < 4; ++r) mm = fmaxf(mm, S[g][t][r]);           \
        mm = fmaxf(mm, __shfl_xor(mm, 16));                                   \
        mm = fmaxf(mm, __shfl_xor(mm, 32));                                   \
        pm[g] = mm;                                                           \
    }                                                                         \
    if (__any((pm[0] > m_run[0]) | (pm[1] > m_run[1]))) {                     \
        _Pragma("unroll")                                                     \
        for (int g = 0; g < 2; ++g) {                                         \
            const float mn = fmaxf(m_run[g], pm[g]);                          \
            const float al = __builtin_amdgcn_exp2f(m_run[g] - mn);           \
            m_run[g] = mn;                                                    \
            l_run[g] *= al;                                                   \
            _Pragma("unroll")                                                 \
            for (int dt = 0; dt < 4; ++dt) o[g][dt] *= al;                    \
        }                                                                     \
    }                                                                         \
    _Pragma("unroll")                                                         \
    for (int g = 0; g < 2; ++g) {                                             \
        float ps = 0.f;                                                       \
        _Pragma("unroll")                                                     \
        for (int t = 0; t < 4; ++t)                                           \
            _Pragma("unroll")                                                 \
            for (int r = 0; r < 4; ++r) {                                     \
                S[g][t][r] = __builtin_amdgcn_exp2f(S[g][t][r] - m_run[g]);   \
                ps += S[g][t][r];                                             \
            }                                                                 \
        ps += __shfl_xor(ps, 16);                                             \
        ps += __shfl_xor(ps, 32);                                             \
        l_run[g] += ps;                                                       \
    }                                                                         \
    _Pragma("unroll")                                                         \
    for (int g = 0; g < 2; ++g) {                                             \
        const int row = 32 * w + 16 * g + lr;                                 \
        _Pragma("unroll")                                                     \
        for (int t = 0; t < 4; ++t) {                                         \
            f16x4 pk = {(f16)S[g][t][0], (f16)S[g][t][1],                     \
                        (f16)S[g][t][2], (f16)S[g][t][3]};                    \
            const int col = (16 * t + 4 * lc) ^ ((lr & 7) << 3);              \
            *(f16x4*)&Ps[row * 64 + col] = pk;                                \
        }                                                                     \
    }                                                                         \
    {                                                                         \
        f16x8 pb[2][2];                                                       \
        _Pragma("unroll")                                                     \
        for (int g = 0; g < 2; ++g) {                                         \
            const int row = 32 * w + 16 * g + lr;                             \
            pb[g][0] = *(const f16x8*)&Ps[row * 64 + swz0];                   \
            pb[g][1] = *(const f16x8*)&Ps[row * 64 + swz1];                   \
        }                                                                     \
        _Pragma("unroll")                                                     \
        for (int dt = 0; dt < 4; ++dt) {                                      \
            f16x8 va0 = *(const f16x8*)&VtB[VB][(dt * 16 + lr) * 64 + swz0];  \
            f16x8 va1 = *(const f16x8*)&VtB[VB][(dt * 16 + lr) * 64 + swz1];  \
            _Pragma("unroll")                                                 \
            for (int g = 0; g < 2; ++g)                                       \
                o[g][dt] = MFMA16(va1, pb[g][1],                              \
                                  MFMA16(va0, pb[g][0], o[g][dt]));           \
        }                                                                     \
    } }

// BODY(j, u=j&3): prefetch(j+1) | QK^T(j)->SCUR | finish(j-1) on SPRV | bar.
#define BODY(J, U, SCUR, SPRV) {                                              \
    if ((J) + 1 < NT) PREFETCH((J) + 1, ((U) + 1) & 1, ((U) + 1) & 3);        \
    QKT((U) & 1, SCUR);                                                       \
    if ((J) > 0) FINISH(((U) + 3) & 3, SPRV);                                 \
    __syncthreads();                                                          \
    }

    PREFETCH(0, 0, 0);
    __syncthreads();

    BODY(0, 0, sA, sB);
    BODY(1, 1, sB, sA);
    BODY(2, 2, sA, sB);
    BODY(3, 3, sB, sA);
    for (int m = 1; m < 8; ++m) {
        const int j = 4 * m;
        BODY(j, 0, sA, sB);
        BODY(j + 1, 1, sB, sA);
        BODY(j + 2, 2, sA, sB);
        BODY(j + 3, 3, sB, sA);
    }
    FINISH(3, sB);                               // tile 31: V[31&3], s = sB

#undef BODY
#undef FINISH
#undef QKT
#undef PREFETCH

    // ---- epilogue: per-split normalized O (f16) + (m,l)
#pragma unroll
    for (int g = 0; g < 2; ++g) {
        const float linv = 1.0f / l_run[g];
        const size_t qg = (size_t)qb * 128 + 32 * w + 16 * g + lr;
        f16* ob = Opart + (((size_t)(sp * 8 + h)) * NSEQ + qg) * DHEAD;
#pragma unroll
        for (int dt = 0; dt < 4; ++dt) {
            f16x4 ov = {(f16)(o[g][dt][0] * linv), (f16)(o[g][dt][1] * linv),
                        (f16)(o[g][dt][2] * linv), (f16)(o[g][dt][3] * linv)};
            *(f16x4*)&ob[dt * 16 + 4 * lc] = ov;
        }
        if (lc == 0) {
            float2 ml = make_float2(m_run[g], l_run[g]);
            *(float2*)&Ml[(((size_t)(sp * 8 + h)) * NSEQ + qg) * 2] = ml;
        }
    }
}

// ---------------------------------------------------------------------------
// kv-split combine, ONE pass (was done 10x redundantly inside out_gemm):
// aoh[q][h*64+d] = normalized weighted sum of the two split partials.
// ---------------------------------------------------------------------------
__global__ __launch_bounds__(256) void combine_o(
    const f16* __restrict__ Opart, const float* __restrict__ Ml,
    f16* __restrict__ aoh)
{
    const int idx = (blockIdx.x * 256 + threadIdx.x) * 8;  // over 4096*512
    const int q = idx >> 9;
    const int c = idx & 511;
    const int h = c >> 6, d = c & 63;
    f16x8 o0 = *(const f16x8*)&Opart[((size_t)h * NSEQ + q) * DHEAD + d];
    f16x8 o1 = *(const f16x8*)&Opart[((size_t)(8 + h) * NSEQ + q) * DHEAD + d];
    float2 ml0 = *(const float2*)&Ml[((size_t)h * NSEQ + q) * 2];
    float2 ml1 = *(const float2*)&Ml[((size_t)(8 + h) * NSEQ + q) * 2];
    const float mx = fmaxf(ml0.x, ml1.x);
    float w0 = ml0.y * __builtin_amdgcn_exp2f(ml0.x - mx);
    float w1 = ml1.y * __builtin_amdgcn_exp2f(ml1.x - mx);
    const float inv = 1.0f / (w0 + w1);
    w0 *= inv; w1 *= inv;
    f16x8 a8;
#pragma unroll
    for (int e = 0; e < 8; ++e)
        a8[e] = (f16)((float)o0[e] * w0 + (float)o1[e] * w1);
    *(f16x8*)&aoh[idx] = a8;
}

// ---------------------------------------------------------------------------
// Output projection, lean: C[4096][640] = aoh[4096][512] @ WoT^T + bo.
// A and B both staged via gl16 (combine removed). M64 x N64, K-step 64.
// ---------------------------------------------------------------------------
__global__ __launch_bounds__(256) void out_gemm16(
    const f16* __restrict__ aoh, const f16* __restrict__ WoT,
    const float* __restrict__ bias, float* __restrict__ C)
{
    __shared__ __align__(16) f16 Xs[4096];
    __shared__ __align__(16) f16 Ws[4096];

    const int bx = blockIdx.x;   // N-tile 0..9
    const int by = blockIdx.y;   // M-tile 0..63
    const int tid = threadIdx.x;
    const int w = tid >> 6, lane = tid & 63;
    const int lr = lane & 15, lc = lane >> 4;
    const int srow8 = lane >> 3;
    const int le = 8 * ((lane & 7) ^ srow8);
    const int swz0 = 8 * (lc ^ (lr & 7));
    const int swz1 = 8 * ((lc + 4) ^ (lr & 7));
    const int m0 = by * 64, n0 = bx * 64;

    f32x4 acc[4] = {};

    for (int s8 = 0; s8 < 8; ++s8) {
        const int k0 = s8 * 64;
#pragma unroll
        for (int c = 0; c < 2; ++c) {
            const int cc = w * 2 + c;
            gl16(aoh + (size_t)(m0 + cc * 8 + srow8) * INNER + k0 + le,
                 &Xs[cc * 512]);
            gl16(WoT + (size_t)(n0 + cc * 8 + srow8) * INNER + k0 + le,
                 &Ws[cc * 512]);
        }
        __syncthreads();
        f16x8 a0 = *(const f16x8*)&Xs[(16 * w + lr) * 64 + swz0];
        f16x8 a1 = *(const f16x8*)&Xs[(16 * w + lr) * 64 + swz1];
#pragma unroll
        for (int nt = 0; nt < 4; ++nt) {
            f16x8 b0 = *(const f16x8*)&Ws[(nt * 16 + lr) * 64 + swz0];
            f16x8 b1 = *(const f16x8*)&Ws[(nt * 16 + lr) * 64 + swz1];
            acc[nt] = MFMA16(a1, b1, MFMA16(a0, b0, acc[nt]));
        }
        __syncthreads();
    }

#pragma unroll
    for (int nt = 0; nt < 4; ++nt) {
        const float b = bias[n0 + nt * 16 + lr];
#pragma unroll
        for (int r = 0; r < 4; ++r)
            C[(size_t)(m0 + 16 * w + lc * 4 + r) * DMODEL + n0 + nt * 16 + lr] =
                acc[nt][r] + b;
    }
}

extern "C" void kernel_launch(void* const* d_in, const int* in_sizes, int n_in,
                              void* d_out, int out_size, void* d_ws, size_t ws_size,
                              hipStream_t stream) {
    const float* x  = (const float*)d_in[0];
    const float* Wq = (const float*)d_in[1];
    const float* Wk = (const float*)d_in[2];
    const float* Wv = (const float*)d_in[3];
    const float* Wo = (const float*)d_in[4];
    const float* bo = (const float*)d_in[5];
    float* out = (float*)d_out;

    // Workspace layout (bytes). Opart overlays WTq/WTk/WTv (disjoint
    // lifetimes: WT die at qkv_gemm16 end; Opart born in attn_fwd).
    char* base = (char*)d_ws;
    f16*   Opart = (f16*)base;                   // 2*8*4096*64*2 = 8,388,608
    f16*   WTq   = (f16*)base;                   // 655,360
    f16*   WTk   = WTq + (size_t)INNER * DMODEL;
    f16*   WTv   = WTk + (size_t)INNER * DMODEL; // ends 1,966,080 < 8,388,608
    float* Ml    = (float*)(base + 8388608);     // 524,288
    f16*   WoT   = (f16*)(base + 8912896);       // 655,360
    f16*   q16   = (f16*)(base + 9568256);       // 4,194,304
    f16*   k16   = q16 + (size_t)NHEAD * NSEQ * DHEAD;
    f16*   vT16  = k16 + (size_t)NHEAD * NSEQ * DHEAD;  // ends 22,151,168
    f16*   aoh   = (f16*)(base + 22151168);      // 4,194,304 -> ends 26,345,472

    transpose_cvtW<<<dim3(10, 10, 4), 256, 0, stream>>>(
        Wq, Wk, Wv, Wo, WTq, WTk, WTv, WoT);

    qkv_gemm16<<<dim3(NHEAD, NSEQ / 128, 3), 256, 0, stream>>>(
        x, WTq, WTk, WTv, q16, k16, vT16);
    attn_fwd<<<dim3(NSEQ / 128, NHEAD, KVSPLIT), 256, 0, stream>>>(
        q16, k16, vT16, Opart, Ml);
    combine_o<<<NSEQ * INNER / (256 * 8), 256, 0, stream>>>(Opart, Ml, aoh);
    out_gemm16<<<dim3(DMODEL / 64, NSEQ / 64), 256, 0, stream>>>(
        aoh, WoT, bo, out);
}